// Round 1
// baseline (749.270 us; speedup 1.0000x reference)
//
#include <hip/hip_runtime.h>
#include <hip/hip_bf16.h>
#include <math.h>

// SS2D (VMamba) forward, MI355X. Constants from the reference.
#define DM 96
#define DI 192
#define NS 16            // state dim N
#define KK 4             // directions
#define RR 6             // dt rank
#define HH 56
#define WW 56
#define LL (HH*WW)       // 3136
#define RN (RR + 2*NS)   // 38 rows of x_dbl
#define CL (LL/4)        // 784 chunk length for the wave-chunked scan

__device__ __forceinline__ float silu_f(float x) { return x / (1.f + expf(-x)); }
__device__ __forceinline__ float softplus_f(float x) {
    return (x > 20.f) ? x : log1pf(expf(x));
}

// K1: xz = x @ in_proj_w^T ; split -> xc (stored (d,l) for conv) and z = silu (stored (l,d))
__global__ void k_inproj(const float* __restrict__ x, const float* __restrict__ w,
                         float* __restrict__ xc_t, float* __restrict__ z) {
    int idx = blockIdx.x * 256 + threadIdx.x;      // idx = o*LL + l
    int o = idx / LL, l = idx % LL;
    const float* xr = x + (size_t)l * DM;
    const float* wr = w + (size_t)o * DM;
    float acc = 0.f;
#pragma unroll 8
    for (int c = 0; c < DM; ++c) acc = fmaf(xr[c], wr[c], acc);
    if (o < DI) xc_t[o * LL + l] = acc;
    else        z[l * DI + (o - DI)] = silu_f(acc);
}

// K2: depthwise 3x3 conv SAME + bias + silu, (d,l) layout
__global__ void k_conv(const float* __restrict__ xc_t, const float* __restrict__ cw,
                       const float* __restrict__ cb, float* __restrict__ xconv) {
    int idx = blockIdx.x * 256 + threadIdx.x;      // d*LL + l
    int d = idx / LL, l = idx % LL;
    int h = l / WW, w = l % WW;
    float acc = cb[d];
    const float* base = xc_t + (size_t)d * LL;
    const float* wt = cw + d * 9;
#pragma unroll
    for (int i = 0; i < 3; ++i) {
        int hh = h + i - 1;
        if (hh < 0 || hh >= HH) continue;
#pragma unroll
        for (int j = 0; j < 3; ++j) {
            int ww2 = w + j - 1;
            if (ww2 < 0 || ww2 >= WW) continue;
            acc = fmaf(base[hh * WW + ww2], wt[i * 3 + j], acc);
        }
    }
    xconv[idx] = silu_f(acc);
}

// K2b: per-channel 56x56 spatial transpose: xs1[d][s] = xconv[d][(s%56)*56 + s/56]
__global__ void k_transpose(const float* __restrict__ xconv, float* __restrict__ xs1) {
    __shared__ float lds[LL];
    int d = blockIdx.x;
    const float* in = xconv + (size_t)d * LL;
    for (int i = threadIdx.x; i < LL; i += 256) lds[i] = in[i];
    __syncthreads();
    float* out = xs1 + (size_t)d * LL;
    for (int s = threadIdx.x; s < LL; s += 256)
        out[s] = lds[(s % HH) * WW + s / HH];
}

// K3: x_dbl: tmpS[k][r][s] = sum_d w[k][r][d] * (k odd ? xs1 : xconv)[d][s]
// Stored per-k in the layout its scan traverses sequentially.
__global__ void k_xdbl(const float* __restrict__ xconv, const float* __restrict__ xs1,
                       const float* __restrict__ pw, float* __restrict__ tmpS) {
    __shared__ float xt[DI * 64];                  // 48 KB
    int k = blockIdx.y;
    int l0 = blockIdx.x * 64;
    const float* in = (k & 1) ? xs1 : xconv;
    for (int i = threadIdx.x; i < DI * 64; i += 256) {
        int d = i >> 6, lx = i & 63;
        xt[i] = in[(size_t)d * LL + l0 + lx];
    }
    __syncthreads();
    const float* wk = pw + (size_t)k * RN * DI;
    for (int oi = threadIdx.x; oi < RN * 64; oi += 256) {
        int r = oi >> 6, lx = oi & 63;
        const float* wr = wk + r * DI;
        float acc = 0.f;
#pragma unroll 8
        for (int d = 0; d < DI; ++d) acc = fmaf(xt[(d << 6) + lx], wr[d], acc);
        tmpS[((size_t)k * RN + r) * LL + l0 + lx] = acc;
    }
}

// K4: delta[k][d][s] = softplus( sum_r tmpS[k][r][s]*dtw[k][d][r] + dtb[k][d] )
__global__ void k_delta(const float* __restrict__ tmpS, const float* __restrict__ dtw,
                        const float* __restrict__ dtb, float* __restrict__ delta) {
    int idx = blockIdx.x * 256 + threadIdx.x;      // (k*DI+d)*LL + s
    int s = idx % LL;
    int kd = idx / LL;
    int k = kd / DI;
    const float* wr = dtw + (size_t)kd * RR;
    float acc = dtb[kd];
    const float* tb = tmpS + (size_t)k * RN * LL + s;
#pragma unroll
    for (int r = 0; r < RR; ++r) acc = fmaf(tb[(size_t)r * LL], wr[r], acc);
    delta[idx] = softplus_f(acc);
}

// K5: chunked selective scan. One wave per (k,d); quarter-wave q handles chunk q,
// lane n in [0,16) handles state n. Phase1: chunk-local (prod dA, h_end);
// shuffle-combine carries; Phase2: rescan with carry, reduce over n, atomicAdd into y.
__global__ __launch_bounds__(64) void k_scan(
        const float* __restrict__ delta, const float* __restrict__ tmpS,
        const float* __restrict__ xconv, const float* __restrict__ xs1,
        const float* __restrict__ A_logs, const float* __restrict__ Ds,
        float* __restrict__ y) {
    int b = blockIdx.x;
    int k = b / DI, d = b % DI;
    int lane = threadIdx.x;
    int q = lane >> 4, n = lane & 15;
    int kd = k * DI + d;
    float An = -expf(A_logs[kd * NS + n]);
    float Dv = Ds[kd];
    const float* del  = delta + (size_t)kd * LL;
    const float* uP   = ((k & 1) ? xs1 : xconv) + (size_t)d * LL;
    const float* Brow = tmpS + ((size_t)k * RN + RR + n) * LL;
    const float* Crow = tmpS + ((size_t)k * RN + RR + NS + n) * LL;
    const bool fwd = (k < 2);
    const int t0 = q * CL;

    // Phase 1: chunk-local scan state + dA product
    float P = 1.f, h = 0.f;
    for (int tl = 0; tl < CL; ++tl) {
        int t = t0 + tl;
        int im = fwd ? t : (LL - 1 - t);
        float dl = del[im];
        float u  = uP[im];
        float Bv = Brow[im];
        float dA = expf(dl * An);
        h = fmaf(dA, h, dl * Bv * u);
        P *= dA;
    }
    // Carry combine across quarters (wave lockstep, no barrier needed)
    float hin = 0.f;
#pragma unroll
    for (int qq = 0; qq < 3; ++qq) {
        float he = __shfl(h, qq * 16 + n, 64);
        float Pp = __shfl(P, qq * 16 + n, 64);
        if (q > qq) hin = fmaf(Pp, hin, he);
    }
    // Phase 2: rescan with carry-in, emit y at natural positions
    h = hin;
    for (int tl = 0; tl < CL; ++tl) {
        int t = t0 + tl;
        int im = fwd ? t : (LL - 1 - t);
        float dl = del[im];
        float u  = uP[im];
        float Bv = Brow[im];
        float Cv = Crow[im];
        float dA = expf(dl * An);
        h = fmaf(dA, h, dl * Bv * u);
        float acc = h * Cv;
        acc += __shfl_xor(acc, 8, 64);
        acc += __shfl_xor(acc, 4, 64);
        acc += __shfl_xor(acc, 2, 64);
        acc += __shfl_xor(acc, 1, 64);
        if (n == 0) {
            int p = (k & 1) ? ((im % HH) * WW + im / HH) : im;   // undo spatial transpose
            atomicAdd(&y[(size_t)p * DI + d], fmaf(Dv, u, acc));
        }
    }
}

// K6: LayerNorm over DI (two-pass), gate with z, out-proj DI->DM
__global__ __launch_bounds__(192) void k_lnout(
        const float* __restrict__ y, const float* __restrict__ z,
        const float* __restrict__ lnw, const float* __restrict__ lnb,
        const float* __restrict__ ow, float* __restrict__ out) {
    __shared__ float yv[DI];
    __shared__ float part[8];
    int l = blockIdx.x;
    int tid = threadIdx.x;
    float v = y[(size_t)l * DI + tid];
    // mean
    float s1 = v;
    for (int off = 32; off; off >>= 1) s1 += __shfl_xor(s1, off, 64);
    int wid = tid >> 6;
    if ((tid & 63) == 0) part[wid] = s1;
    __syncthreads();
    float mean = (part[0] + part[1] + part[2]) * (1.f / DI);
    __syncthreads();
    // var (two-pass for accuracy)
    float dv = v - mean;
    float s2 = dv * dv;
    for (int off = 32; off; off >>= 1) s2 += __shfl_xor(s2, off, 64);
    if ((tid & 63) == 0) part[4 + wid] = s2;
    __syncthreads();
    float var = (part[4] + part[5] + part[6]) * (1.f / DI);
    float inv = rsqrtf(var + 1e-5f);
    float yn = dv * inv * lnw[tid] + lnb[tid];
    yv[tid] = yn * z[(size_t)l * DI + tid];
    __syncthreads();
    if (tid < DM) {
        const float* wr = ow + (size_t)tid * DI;
        float acc = 0.f;
#pragma unroll 8
        for (int dd = 0; dd < DI; ++dd) acc = fmaf(yv[dd], wr[dd], acc);
        out[(size_t)l * DM + tid] = acc;
    }
}

extern "C" void kernel_launch(void* const* d_in, const int* in_sizes, int n_in,
                              void* d_out, int out_size, void* d_ws, size_t ws_size,
                              hipStream_t stream) {
    const float* x    = (const float*)d_in[0];
    const float* ipw  = (const float*)d_in[1];
    const float* cw   = (const float*)d_in[2];
    const float* cb   = (const float*)d_in[3];
    const float* xpw  = (const float*)d_in[4];
    const float* dtw  = (const float*)d_in[5];
    const float* dtb  = (const float*)d_in[6];
    const float* alog = (const float*)d_in[7];
    const float* Dsp  = (const float*)d_in[8];
    const float* lnw  = (const float*)d_in[9];
    const float* lnb  = (const float*)d_in[10];
    const float* ow   = (const float*)d_in[11];
    float* out = (float*)d_out;

    // workspace layout (floats): 5,895,680 total ~ 23.6 MB
    float* ws    = (float*)d_ws;
    float* xc_t  = ws;                          // DI*LL
    float* z     = xc_t + DI * LL;              // LL*DI
    float* xconv = z + LL * DI;                 // DI*LL
    float* xs1   = xconv + DI * LL;             // DI*LL
    float* tmpS  = xs1 + DI * LL;               // KK*RN*LL
    float* delta = tmpS + (size_t)KK * RN * LL; // KK*DI*LL
    float* y     = delta + (size_t)KK * DI * LL;// LL*DI

    hipMemsetAsync(y, 0, sizeof(float) * LL * DI, stream);

    k_inproj  <<<(2 * DI * LL) / 256, 256, 0, stream>>>(x, ipw, xc_t, z);
    k_conv    <<<(DI * LL) / 256, 256, 0, stream>>>(xc_t, cw, cb, xconv);
    k_transpose<<<DI, 256, 0, stream>>>(xconv, xs1);
    k_xdbl    <<<dim3(LL / 64, KK), 256, 0, stream>>>(xconv, xs1, xpw, tmpS);
    k_delta   <<<(KK * DI * LL) / 256, 256, 0, stream>>>(tmpS, dtw, dtb, delta);
    k_scan    <<<KK * DI, 64, 0, stream>>>(delta, tmpS, xconv, xs1, alog, Dsp, y);
    k_lnout   <<<LL, 192, 0, stream>>>(y, z, lnw, lnb, ow, out);
}

// Round 2
// 336.056 us; speedup vs baseline: 2.2296x; 2.2296x over previous
//
#include <hip/hip_runtime.h>
#include <hip/hip_bf16.h>
#include <math.h>

// SS2D (VMamba) forward, MI355X. Constants from the reference.
#define DM 96
#define DI 192
#define NS 16            // state dim N
#define KK 4             // directions
#define RR 6             // dt rank
#define HH 56
#define WW 56
#define LL (HH*WW)       // 3136
#define RN (RR + 2*NS)   // 38 rows of x_dbl
#define NCH 64           // scan chunks per sequence
#define CLL (LL/NCH)     // 49 steps per chunk

__device__ __forceinline__ float silu_f(float x) { return x / (1.f + __expf(-x)); }
__device__ __forceinline__ float softplus_f(float x) {
    return (x > 20.f) ? x : log1pf(__expf(x));
}

// K1: xz = x @ in_proj_w^T ; split -> xc (stored (d,l) for conv) and z = silu (stored (l,d))
__global__ void k_inproj(const float* __restrict__ x, const float* __restrict__ w,
                         float* __restrict__ xc_t, float* __restrict__ z) {
    int idx = blockIdx.x * 256 + threadIdx.x;      // idx = o*LL + l
    int o = idx / LL, l = idx % LL;
    const float* xr = x + (size_t)l * DM;
    const float* wr = w + (size_t)o * DM;
    float acc = 0.f;
#pragma unroll 8
    for (int c = 0; c < DM; ++c) acc = fmaf(xr[c], wr[c], acc);
    if (o < DI) xc_t[o * LL + l] = acc;
    else        z[l * DI + (o - DI)] = silu_f(acc);
}

// K2: depthwise 3x3 conv SAME + bias + silu, (d,l) layout
__global__ void k_conv(const float* __restrict__ xc_t, const float* __restrict__ cw,
                       const float* __restrict__ cb, float* __restrict__ xconv) {
    int idx = blockIdx.x * 256 + threadIdx.x;      // d*LL + l
    int d = idx / LL, l = idx % LL;
    int h = l / WW, w = l % WW;
    float acc = cb[d];
    const float* base = xc_t + (size_t)d * LL;
    const float* wt = cw + d * 9;
#pragma unroll
    for (int i = 0; i < 3; ++i) {
        int hh = h + i - 1;
        if (hh < 0 || hh >= HH) continue;
#pragma unroll
        for (int j = 0; j < 3; ++j) {
            int ww2 = w + j - 1;
            if (ww2 < 0 || ww2 >= WW) continue;
            acc = fmaf(base[hh * WW + ww2], wt[i * 3 + j], acc);
        }
    }
    xconv[idx] = silu_f(acc);
}

// K2b: per-channel 56x56 spatial transpose: xs1[d][s] = xconv[d][(s%56)*56 + s/56]
__global__ void k_transpose(const float* __restrict__ xconv, float* __restrict__ xs1) {
    __shared__ float lds[LL];
    int d = blockIdx.x;
    const float* in = xconv + (size_t)d * LL;
    for (int i = threadIdx.x; i < LL; i += 256) lds[i] = in[i];
    __syncthreads();
    float* out = xs1 + (size_t)d * LL;
    for (int s = threadIdx.x; s < LL; s += 256)
        out[s] = lds[(s % HH) * WW + s / HH];
}

// K3: x_dbl rows. dt rows -> dtr[k][r][s] (row-major, for k_delta).
// B rows -> Bn[k][s][n] interleaved; C rows -> Cn[k][s][n]  (scan-coalesced).
__global__ void k_xdbl(const float* __restrict__ xconv, const float* __restrict__ xs1,
                       const float* __restrict__ pw, float* __restrict__ dtr,
                       float* __restrict__ Bn, float* __restrict__ Cn) {
    __shared__ float xt[DI * 64];                  // 48 KB
    int k = blockIdx.y;
    int l0 = blockIdx.x * 64;
    const float* in = (k & 1) ? xs1 : xconv;
    for (int i = threadIdx.x; i < DI * 64; i += 256) {
        int d = i >> 6, lx = i & 63;
        xt[i] = in[(size_t)d * LL + l0 + lx];
    }
    __syncthreads();
    const float* wk = pw + (size_t)k * RN * DI;
    // dt rows (RR x 64)
    for (int oi = threadIdx.x; oi < RR * 64; oi += 256) {
        int r = oi >> 6, lx = oi & 63;
        const float* wr = wk + r * DI;
        float acc = 0.f;
#pragma unroll 8
        for (int d = 0; d < DI; ++d) acc = fmaf(xt[(d << 6) + lx], wr[d], acc);
        dtr[((size_t)k * RR + r) * LL + l0 + lx] = acc;
    }
    // B/C rows: 64 s-positions x 32 cols (B: col<16, C: col>=16), n-contig writes
    for (int oi = threadIdx.x; oi < 64 * 32; oi += 256) {
        int sl = oi >> 5, col = oi & 31;
        const float* wr = wk + (RR + col) * DI;
        float acc = 0.f;
#pragma unroll 8
        for (int d = 0; d < DI; ++d) acc = fmaf(xt[(d << 6) + sl], wr[d], acc);
        int s = l0 + sl;
        if (col < NS) Bn[((size_t)k * LL + s) * NS + col] = acc;
        else          Cn[((size_t)k * LL + s) * NS + (col - NS)] = acc;
    }
}

// K4: delta[kd][s] = softplus( sum_r dtr[k][r][s]*dtw[kd][r] + dtb[kd] )
__global__ void k_delta(const float* __restrict__ dtr, const float* __restrict__ dtw,
                        const float* __restrict__ dtb, float* __restrict__ delta) {
    int idx = blockIdx.x * 256 + threadIdx.x;      // (k*DI+d)*LL + s
    int s = idx % LL;
    int kd = idx / LL;
    int k = kd / DI;
    const float* wr = dtw + (size_t)kd * RR;
    float acc = dtb[kd];
    const float* tb = dtr + (size_t)k * RR * LL + s;
#pragma unroll
    for (int r = 0; r < RR; ++r) acc = fmaf(tb[(size_t)r * LL], wr[r], acc);
    delta[idx] = softplus_f(acc);
}

// K5: chunked selective scan, 64 chunks x 49 steps, one (k,d) per 1024-thread block.
// 16-lane group per chunk (lane n = state). Phase1: (prod dA, h_end) per chunk;
// LDS carry fold; Phase2: rescan with carry, n-reduce, coalesced stores to ybuf.
__global__ __launch_bounds__(1024) void k_scan(
        const float* __restrict__ delta, const float* __restrict__ Bn,
        const float* __restrict__ Cn,
        const float* __restrict__ xconv, const float* __restrict__ xs1,
        const float* __restrict__ A_logs, const float* __restrict__ Ds,
        float* __restrict__ ybuf) {
    int b = blockIdx.x;
    int k = b / DI, d = b % DI;
    int tid = threadIdx.x;
    int c = tid >> 4, n = tid & 15;
    int kd = k * DI + d;
    float An = -__expf(A_logs[kd * NS + n]);
    float Dv = Ds[kd];
    const float* del = delta + (size_t)kd * LL;
    const float* uP  = ((k & 1) ? xs1 : xconv) + (size_t)d * LL;
    const float* Bb  = Bn + (size_t)k * LL * NS;
    const float* Cb  = Cn + (size_t)k * LL * NS;
    const bool fwd = (k < 2);
    const int t0 = c * CLL;

    // Phase 1: chunk-local scan (start h=0), track product of dA
    float P = 1.f, h = 0.f;
    for (int tl = 0; tl < CLL; ++tl) {
        int t = t0 + tl;
        int im = fwd ? t : (LL - 1 - t);
        float dl = del[im];
        float u  = uP[im];
        float Bv = Bb[im * NS + n];
        float dA = __expf(dl * An);
        h = fmaf(dA, h, dl * Bv * u);
        P *= dA;
    }
    __shared__ float sP[NCH * NS];
    __shared__ float sH[NCH * NS];
    sP[c * NS + n] = P;
    sH[c * NS + n] = h;
    __syncthreads();
    // carry-in for chunk c: fold chunks 0..c-1 in order
    float hin = 0.f;
    for (int cc = 0; cc < c; ++cc)
        hin = fmaf(sP[cc * NS + n], hin, sH[cc * NS + n]);

    // Phase 2: rescan with carry, emit y (register-batched coalesced stores)
    float h2 = hin;
    float yreg[4];
    for (int tl = 0; tl < CLL; ++tl) {
        int t = t0 + tl;
        int im = fwd ? t : (LL - 1 - t);
        float dl = del[im];
        float u  = uP[im];
        float Bv = Bb[im * NS + n];
        float Cv = Cb[im * NS + n];
        float dA = __expf(dl * An);
        h2 = fmaf(dA, h2, dl * Bv * u);
        float acc = h2 * Cv;
        acc += __shfl_xor(acc, 8, 64);
        acc += __shfl_xor(acc, 4, 64);
        acc += __shfl_xor(acc, 2, 64);
        acc += __shfl_xor(acc, 1, 64);
        acc = fmaf(Dv, u, acc);
        if ((tl & 15) == n) yreg[tl >> 4] = acc;
    }
    float* yo = ybuf + (size_t)kd * LL;
#pragma unroll
    for (int j = 0; j < 3; ++j) {
        int t = t0 + j * 16 + n;
        int im = fwd ? t : (LL - 1 - t);
        yo[im] = yreg[j];
    }
    if (n == 0) {
        int t = t0 + 48;
        int im = fwd ? t : (LL - 1 - t);
        yo[im] = yreg[3];
    }
}

// K6: merge 4 directions + LayerNorm over DI + gate with z + out-proj DI->DM
__global__ __launch_bounds__(192) void k_lnout(
        const float* __restrict__ ybuf, const float* __restrict__ z,
        const float* __restrict__ lnw, const float* __restrict__ lnb,
        const float* __restrict__ ow, float* __restrict__ out) {
    __shared__ float yv[DI];
    __shared__ float part[8];
    int l = blockIdx.x;
    int tid = threadIdx.x;
    int pT = (l % WW) * HH + (l / WW);   // transposed-space index of position l
    float v = ybuf[((size_t)(0 * DI) + tid) * LL + l]
            + ybuf[((size_t)(2 * DI) + tid) * LL + l]
            + ybuf[((size_t)(1 * DI) + tid) * LL + pT]
            + ybuf[((size_t)(3 * DI) + tid) * LL + pT];
    // mean
    float s1 = v;
    for (int off = 32; off; off >>= 1) s1 += __shfl_xor(s1, off, 64);
    int wid = tid >> 6;
    if ((tid & 63) == 0) part[wid] = s1;
    __syncthreads();
    float mean = (part[0] + part[1] + part[2]) * (1.f / DI);
    __syncthreads();
    // var (two-pass)
    float dv = v - mean;
    float s2 = dv * dv;
    for (int off = 32; off; off >>= 1) s2 += __shfl_xor(s2, off, 64);
    if ((tid & 63) == 0) part[4 + wid] = s2;
    __syncthreads();
    float var = (part[4] + part[5] + part[6]) * (1.f / DI);
    float inv = rsqrtf(var + 1e-5f);
    float yn = dv * inv * lnw[tid] + lnb[tid];
    yv[tid] = yn * z[(size_t)l * DI + tid];
    __syncthreads();
    if (tid < DM) {
        const float* wr = ow + (size_t)tid * DI;
        float acc = 0.f;
#pragma unroll 8
        for (int dd = 0; dd < DI; ++dd) acc = fmaf(yv[dd], wr[dd], acc);
        out[(size_t)l * DM + tid] = acc;
    }
}

extern "C" void kernel_launch(void* const* d_in, const int* in_sizes, int n_in,
                              void* d_out, int out_size, void* d_ws, size_t ws_size,
                              hipStream_t stream) {
    const float* x    = (const float*)d_in[0];
    const float* ipw  = (const float*)d_in[1];
    const float* cw   = (const float*)d_in[2];
    const float* cb   = (const float*)d_in[3];
    const float* xpw  = (const float*)d_in[4];
    const float* dtw  = (const float*)d_in[5];
    const float* dtb  = (const float*)d_in[6];
    const float* alog = (const float*)d_in[7];
    const float* Dsp  = (const float*)d_in[8];
    const float* lnw  = (const float*)d_in[9];
    const float* lnb  = (const float*)d_in[10];
    const float* ow   = (const float*)d_in[11];
    float* out = (float*)d_out;

    // workspace layout (floats): ~7.7M floats ~ 31 MB
    float* ws    = (float*)d_ws;
    float* xc_t  = ws;                            // DI*LL
    float* z     = xc_t + DI * LL;                // LL*DI
    float* xconv = z + LL * DI;                   // DI*LL
    float* xs1   = xconv + DI * LL;               // DI*LL
    float* dtr   = xs1 + DI * LL;                 // KK*RR*LL
    float* Bn    = dtr + (size_t)KK * RR * LL;    // KK*LL*NS
    float* Cn    = Bn + (size_t)KK * LL * NS;     // KK*LL*NS
    float* delta = Cn + (size_t)KK * LL * NS;     // KK*DI*LL
    float* ybuf  = delta + (size_t)KK * DI * LL;  // KK*DI*LL

    k_inproj  <<<(2 * DI * LL) / 256, 256, 0, stream>>>(x, ipw, xc_t, z);
    k_conv    <<<(DI * LL) / 256, 256, 0, stream>>>(xc_t, cw, cb, xconv);
    k_transpose<<<DI, 256, 0, stream>>>(xconv, xs1);
    k_xdbl    <<<dim3(LL / 64, KK), 256, 0, stream>>>(xconv, xs1, xpw, dtr, Bn, Cn);
    k_delta   <<<(KK * DI * LL) / 256, 256, 0, stream>>>(dtr, dtw, dtb, delta);
    k_scan    <<<KK * DI, 1024, 0, stream>>>(delta, Bn, Cn, xconv, xs1, alog, Dsp, ybuf);
    k_lnout   <<<LL, 192, 0, stream>>>(ybuf, z, lnw, lnb, ow, out);
}

// Round 3
// 226.451 us; speedup vs baseline: 3.3088x; 1.4840x over previous
//
#include <hip/hip_runtime.h>
#include <hip/hip_bf16.h>
#include <math.h>

// SS2D (VMamba) forward, MI355X. Constants from the reference.
#define DM 96
#define DI 192
#define NS 16            // state dim N
#define KK 4             // directions
#define RR 6             // dt rank
#define HH 56
#define WW 56
#define LL (HH*WW)       // 3136
#define RN (RR + 2*NS)   // 38 rows of x_dbl
#define NCH 64           // scan chunks per sequence
#define CLL (LL/NCH)     // 49 steps per chunk

__device__ __forceinline__ float silu_f(float x) { return x / (1.f + __expf(-x)); }
__device__ __forceinline__ float softplus_f(float x) {
    return (x > 20.f) ? x : log1pf(__expf(x));
}

// K1: tiled GEMM  xz[o][l] = sum_c x[l][c] * w[o][c]; o<DI -> xc_t[o][l], o>=DI -> silu -> z_t[o-DI][l]
// 64l x 64o tile per block, 256 threads, stride-16 register blocking (LDS conflicts <=2-way = free).
__global__ __launch_bounds__(256) void k_inproj(
        const float* __restrict__ x, const float* __restrict__ w,
        float* __restrict__ xc_t, float* __restrict__ z_t) {
    __shared__ float smem[2 * 64 * 100];          // xt | wt, 51.2 KB
    float* xt = smem;
    float* wt = smem + 64 * 100;
    const int l0 = blockIdx.x * 64;
    const int o0 = blockIdx.y * 64;
    const int tid = threadIdx.x;
    for (int i = tid; i < 64 * 96; i += 256) {
        int r = i / 96, c = i % 96;
        xt[r * 100 + c] = x[(size_t)(l0 + r) * DM + c];
        wt[r * 100 + c] = w[(size_t)(o0 + r) * DM + c];
    }
    __syncthreads();
    const int tx = tid & 15, ty = tid >> 4;
    float acc[4][4] = {};
    for (int c = 0; c < 96; c += 4) {
        float4 av[4], bv[4];
#pragma unroll
        for (int i = 0; i < 4; ++i) av[i] = *(const float4*)&xt[(ty + 16 * i) * 100 + c];
#pragma unroll
        for (int j = 0; j < 4; ++j) bv[j] = *(const float4*)&wt[(tx + 16 * j) * 100 + c];
#pragma unroll
        for (int i = 0; i < 4; ++i)
#pragma unroll
            for (int j = 0; j < 4; ++j) {
                acc[i][j] = fmaf(av[i].x, bv[j].x, acc[i][j]);
                acc[i][j] = fmaf(av[i].y, bv[j].y, acc[i][j]);
                acc[i][j] = fmaf(av[i].z, bv[j].z, acc[i][j]);
                acc[i][j] = fmaf(av[i].w, bv[j].w, acc[i][j]);
            }
    }
    __syncthreads();
    float* ot = smem;                              // reuse (64x65 <= 64x100)
#pragma unroll
    for (int j = 0; j < 4; ++j)
#pragma unroll
        for (int i = 0; i < 4; ++i)
            ot[(tx + 16 * j) * 65 + (ty + 16 * i)] = acc[i][j];
    __syncthreads();
    for (int i = tid; i < 64 * 64; i += 256) {
        int ol = i >> 6, ll = i & 63;
        float v = ot[ol * 65 + ll];
        int o = o0 + ol;
        if (o < DI) xc_t[(size_t)o * LL + l0 + ll] = v;
        else        z_t[(size_t)(o - DI) * LL + l0 + ll] = silu_f(v);
    }
}

// K2: depthwise 3x3 conv SAME + bias + silu, fused with spatial transpose.
// One block per channel d: writes xconv[d][l] (natural) and xs1[d][s] (transposed).
__global__ __launch_bounds__(256) void k_convT(
        const float* __restrict__ xc_t, const float* __restrict__ cw,
        const float* __restrict__ cb, float* __restrict__ xconv, float* __restrict__ xs1) {
    __shared__ float in_s[LL];
    __shared__ float out_s[HH * 57];               // padded rows for transpose read
    const int d = blockIdx.x;
    const int tid = threadIdx.x;
    const float* in = xc_t + (size_t)d * LL;
    for (int i = tid; i < LL; i += 256) in_s[i] = in[i];
    __syncthreads();
    const float b0 = cb[d];
    const float* wt = cw + d * 9;
    float w9[9];
#pragma unroll
    for (int i = 0; i < 9; ++i) w9[i] = wt[i];
    for (int l = tid; l < LL; l += 256) {
        int h = l / WW, w = l % WW;
        float acc = b0;
#pragma unroll
        for (int i = 0; i < 3; ++i) {
            int hh = h + i - 1;
            if (hh < 0 || hh >= HH) continue;
#pragma unroll
            for (int j = 0; j < 3; ++j) {
                int w2 = w + j - 1;
                if (w2 < 0 || w2 >= WW) continue;
                acc = fmaf(in_s[hh * WW + w2], w9[i * 3 + j], acc);
            }
        }
        acc = silu_f(acc);
        xconv[(size_t)d * LL + l] = acc;
        out_s[h * 57 + w] = acc;
    }
    __syncthreads();
    float* xo = xs1 + (size_t)d * LL;
    for (int s = tid; s < LL; s += 256)
        xo[s] = out_s[(s % HH) * 57 + s / HH];
}

// K3: x_dbl + delta fused. Per (l-tile of 64, k):
//  dt rows (r<6) -> LDS, then delta[kd][s]=softplus(.) for all d;
//  B/C rows as mini-GEMM (64s x 32col x 192d) -> Bn/Cn [k][s][n] interleaved.
__global__ __launch_bounds__(256) void k_xdblD(
        const float* __restrict__ xconv, const float* __restrict__ xs1,
        const float* __restrict__ pw, const float* __restrict__ dtw,
        const float* __restrict__ dtb,
        float* __restrict__ Bn, float* __restrict__ Cn, float* __restrict__ delta) {
    __shared__ float wk_s[32 * 193];               // B/C weight rows, 24.7 KB
    __shared__ float dtS[RR * 65];
    const int k = blockIdx.y;
    const int l0 = blockIdx.x * 64;
    const int tid = threadIdx.x;
    const float* in = (k & 1) ? xs1 : xconv;
    const float* wk = pw + (size_t)k * RN * DI;
    for (int i = tid; i < 32 * DI; i += 256) {
        int row = i / DI, d = i % DI;
        wk_s[row * 193 + d] = wk[(RR + row) * DI + d];
    }
    // dt rows: r in [0,6), lanes over l (coalesced global reads, wave-uniform w)
    for (int oi = tid; oi < RR * 64; oi += 256) {
        int r = oi >> 6, lx = oi & 63;
        const float* wr = wk + r * DI;
        float acc = 0.f;
#pragma unroll 8
        for (int d = 0; d < DI; ++d) acc = fmaf(in[(size_t)d * LL + l0 + lx], wr[d], acc);
        dtS[r * 65 + lx] = acc;
    }
    __syncthreads();
    // B/C mini-GEMM: thread owns 2 s x 4 col
    {
        const int sx = tid & 31, cg = tid >> 5;    // cg in [0,8)
        float acc2[2][4] = {};
        const float* inA = in + l0 + sx;
        const float* inB = in + l0 + sx + 32;
#pragma unroll 4
        for (int d = 0; d < DI; ++d) {
            float x0 = inA[(size_t)d * LL];
            float x1 = inB[(size_t)d * LL];
#pragma unroll
            for (int j = 0; j < 4; ++j) {
                float wv = wk_s[(cg + 8 * j) * 193 + d];
                acc2[0][j] = fmaf(x0, wv, acc2[0][j]);
                acc2[1][j] = fmaf(x1, wv, acc2[1][j]);
            }
        }
#pragma unroll
        for (int si = 0; si < 2; ++si) {
            int s = l0 + sx + 32 * si;
#pragma unroll
            for (int j = 0; j < 4; ++j) {
                int col = cg + 8 * j;
                if (col < NS) Bn[((size_t)k * LL + s) * NS + col] = acc2[si][j];
                else          Cn[((size_t)k * LL + s) * NS + (col - NS)] = acc2[si][j];
            }
        }
    }
    // delta for all d of this k, this l-tile
    for (int oi = tid; oi < DI * 64; oi += 256) {
        int d = oi >> 6, sl = oi & 63;
        int kd = k * DI + d;
        const float* wr = dtw + (size_t)kd * RR;
        float acc = dtb[kd];
#pragma unroll
        for (int r = 0; r < RR; ++r) acc = fmaf(dtS[r * 65 + sl], wr[r], acc);
        delta[(size_t)kd * LL + l0 + sl] = softplus_f(acc);
    }
}

// K4: chunked selective scan, 64 chunks x 49 steps, one (k,d) per 1024-thread block.
__global__ __launch_bounds__(1024) void k_scan(
        const float* __restrict__ delta, const float* __restrict__ Bn,
        const float* __restrict__ Cn,
        const float* __restrict__ xconv, const float* __restrict__ xs1,
        const float* __restrict__ A_logs, const float* __restrict__ Ds,
        float* __restrict__ ybuf) {
    int b = blockIdx.x;
    int k = b / DI, d = b % DI;
    int tid = threadIdx.x;
    int c = tid >> 4, n = tid & 15;
    int kd = k * DI + d;
    float An = -__expf(A_logs[kd * NS + n]);
    float Dv = Ds[kd];
    const float* del = delta + (size_t)kd * LL;
    const float* uP  = ((k & 1) ? xs1 : xconv) + (size_t)d * LL;
    const float* Bb  = Bn + (size_t)k * LL * NS;
    const float* Cb  = Cn + (size_t)k * LL * NS;
    const bool fwd = (k < 2);
    const int t0 = c * CLL;
    const int im0 = fwd ? t0 : (LL - 1 - t0);
    const int stp = fwd ? 1 : -1;

    // Phase 1: chunk-local scan (h=0 start), track product of dA
    {
        const float* pd = del + im0;
        const float* pu = uP + im0;
        const float* pB = Bb + (size_t)im0 * NS + n;
        float P = 1.f, h = 0.f;
#pragma unroll 7
        for (int tl = 0; tl < CLL; ++tl) {
            float dl = *pd; float u = *pu; float Bv = *pB;
            pd += stp; pu += stp; pB += stp * NS;
            float dA = __expf(dl * An);
            h = fmaf(dA, h, dl * Bv * u);
            P *= dA;
        }
        __shared__ float sP[NCH * NS];
        __shared__ float sH[NCH * NS];
        sP[c * NS + n] = P;
        sH[c * NS + n] = h;
        __syncthreads();
        float hin = 0.f;
        for (int cc = 0; cc < c; ++cc)
            hin = fmaf(sP[cc * NS + n], hin, sH[cc * NS + n]);
        // Phase 2: rescan with carry, emit y (register-batched coalesced stores)
        float h2 = hin;
        float yreg[4];
        const float* pd2 = del + im0;
        const float* pu2 = uP + im0;
        const float* pB2 = Bb + (size_t)im0 * NS + n;
        const float* pC2 = Cb + (size_t)im0 * NS + n;
#pragma unroll 7
        for (int tl = 0; tl < CLL; ++tl) {
            float dl = *pd2; float u = *pu2; float Bv = *pB2; float Cv = *pC2;
            pd2 += stp; pu2 += stp; pB2 += stp * NS; pC2 += stp * NS;
            float dA = __expf(dl * An);
            h2 = fmaf(dA, h2, dl * Bv * u);
            float acc = h2 * Cv;
            acc += __shfl_xor(acc, 8, 64);
            acc += __shfl_xor(acc, 4, 64);
            acc += __shfl_xor(acc, 2, 64);
            acc += __shfl_xor(acc, 1, 64);
            acc = fmaf(Dv, u, acc);
            if ((tl & 15) == n) yreg[tl >> 4] = acc;
        }
        float* yo = ybuf + (size_t)kd * LL;
#pragma unroll
        for (int j = 0; j < 3; ++j) {
            int t = t0 + j * 16 + n;
            int im = fwd ? t : (LL - 1 - t);
            yo[im] = yreg[j];
        }
        if (n == 0) {
            int t = t0 + 48;
            int im = fwd ? t : (LL - 1 - t);
            yo[im] = yreg[3];
        }
    }
}

// K5: merge 4 directions + LayerNorm + gate(z) + out-proj (DI->DM), 16 l per block.
// ow staged in LDS in two 48-row passes (static LDS < 64 KB).
__global__ __launch_bounds__(256) void k_lnout(
        const float* __restrict__ ybuf, const float* __restrict__ z_t,
        const float* __restrict__ lnw, const float* __restrict__ lnb,
        const float* __restrict__ ow, float* __restrict__ out) {
    __shared__ float ow_s[48 * 196];               // 37.6 KB
    __shared__ float yv_s[16 * 196];               // 12.5 KB
    __shared__ float mean_s[16], inv_s[16];
    const int l0 = blockIdx.x * 16;
    const int tid = threadIdx.x;
    // merge 4 directions into yv_s[ll][d]
    for (int i = tid; i < DI * 16; i += 256) {
        int d = i >> 4, ll = i & 15;
        int l = l0 + ll;
        int pT = (l % WW) * HH + l / WW;
        float v = ybuf[((size_t)(0 * DI) + d) * LL + l]
                + ybuf[((size_t)(2 * DI) + d) * LL + l]
                + ybuf[((size_t)(1 * DI) + d) * LL + pT]
                + ybuf[((size_t)(3 * DI) + d) * LL + pT];
        yv_s[ll * 196 + d] = v;
    }
    __syncthreads();
    // LN stats: 16 threads per l
    {
        int ll = tid >> 4, e = tid & 15;
        float s1 = 0.f;
#pragma unroll
        for (int m = 0; m < 12; ++m) s1 += yv_s[ll * 196 + e + 16 * m];
        s1 += __shfl_xor(s1, 8, 64);
        s1 += __shfl_xor(s1, 4, 64);
        s1 += __shfl_xor(s1, 2, 64);
        s1 += __shfl_xor(s1, 1, 64);
        float mean = s1 * (1.f / DI);
        float s2 = 0.f;
#pragma unroll
        for (int m = 0; m < 12; ++m) {
            float dv = yv_s[ll * 196 + e + 16 * m] - mean;
            s2 = fmaf(dv, dv, s2);
        }
        s2 += __shfl_xor(s2, 8, 64);
        s2 += __shfl_xor(s2, 4, 64);
        s2 += __shfl_xor(s2, 2, 64);
        s2 += __shfl_xor(s2, 1, 64);
        if (e == 0) {
            mean_s[ll] = mean;
            inv_s[ll] = rsqrtf(s2 * (1.f / DI) + 1e-5f);
        }
    }
    __syncthreads();
    // normalize + gate
    for (int i = tid; i < DI * 16; i += 256) {
        int d = i >> 4, ll = i & 15;
        float yn = (yv_s[ll * 196 + d] - mean_s[ll]) * inv_s[ll] * lnw[d] + lnb[d];
        yv_s[ll * 196 + d] = yn * z_t[(size_t)d * LL + l0 + ll];
    }
    __syncthreads();
    // out-proj in two 48-row passes
    const int lg = tid >> 4, og = tid & 15;
#pragma unroll
    for (int pass = 0; pass < 2; ++pass) {
        for (int i = tid; i < 48 * DI; i += 256) {
            int o = i / DI, dd = i % DI;
            ow_s[o * 196 + dd] = ow[(size_t)(pass * 48 + o) * DI + dd];
        }
        __syncthreads();
        float acc[3] = {0.f, 0.f, 0.f};
        for (int dd = 0; dd < DI; dd += 4) {
            float4 yv4 = *(const float4*)&yv_s[lg * 196 + dd];
#pragma unroll
            for (int j = 0; j < 3; ++j) {
                float4 ov = *(const float4*)&ow_s[(og + 16 * j) * 196 + dd];
                acc[j] = fmaf(yv4.x, ov.x, acc[j]);
                acc[j] = fmaf(yv4.y, ov.y, acc[j]);
                acc[j] = fmaf(yv4.z, ov.z, acc[j]);
                acc[j] = fmaf(yv4.w, ov.w, acc[j]);
            }
        }
#pragma unroll
        for (int j = 0; j < 3; ++j)
            out[(size_t)(l0 + lg) * DM + pass * 48 + og + 16 * j] = acc[j];
        __syncthreads();
    }
}

extern "C" void kernel_launch(void* const* d_in, const int* in_sizes, int n_in,
                              void* d_out, int out_size, void* d_ws, size_t ws_size,
                              hipStream_t stream) {
    const float* x    = (const float*)d_in[0];
    const float* ipw  = (const float*)d_in[1];
    const float* cw   = (const float*)d_in[2];
    const float* cb   = (const float*)d_in[3];
    const float* xpw  = (const float*)d_in[4];
    const float* dtw  = (const float*)d_in[5];
    const float* dtb  = (const float*)d_in[6];
    const float* alog = (const float*)d_in[7];
    const float* Dsp  = (const float*)d_in[8];
    const float* lnw  = (const float*)d_in[9];
    const float* lnb  = (const float*)d_in[10];
    const float* ow   = (const float*)d_in[11];
    float* out = (float*)d_out;

    // workspace layout (floats): ~7.63M ~ 30.5 MB
    float* ws    = (float*)d_ws;
    float* xc_t  = ws;                            // DI*LL
    float* z_t   = xc_t + DI * LL;                // DI*LL
    float* xconv = z_t + DI * LL;                 // DI*LL
    float* xs1   = xconv + DI * LL;               // DI*LL
    float* Bn    = xs1 + DI * LL;                 // KK*LL*NS
    float* Cn    = Bn + (size_t)KK * LL * NS;     // KK*LL*NS
    float* delta = Cn + (size_t)KK * LL * NS;     // KK*DI*LL
    float* ybuf  = delta + (size_t)KK * DI * LL;  // KK*DI*LL

    k_inproj <<<dim3(LL / 64, 6), 256, 0, stream>>>(x, ipw, xc_t, z_t);
    k_convT  <<<DI, 256, 0, stream>>>(xc_t, cw, cb, xconv, xs1);
    k_xdblD  <<<dim3(LL / 64, KK), 256, 0, stream>>>(xconv, xs1, xpw, dtw, dtb, Bn, Cn, delta);
    k_scan   <<<KK * DI, 1024, 0, stream>>>(delta, Bn, Cn, xconv, xs1, alog, Dsp, ybuf);
    k_lnout  <<<LL / 16, 256, 0, stream>>>(ybuf, z_t, lnw, lnb, ow, out);
}

// Round 4
// 202.313 us; speedup vs baseline: 3.7035x; 1.1193x over previous
//
#include <hip/hip_runtime.h>
#include <hip/hip_bf16.h>
#include <math.h>

// SS2D (VMamba) forward, MI355X. Constants from the reference.
#define DM 96
#define DI 192
#define NS 16            // state dim N
#define KK 4             // directions
#define RR 6             // dt rank
#define HH 56
#define WW 56
#define LL (HH*WW)       // 3136
#define RN (RR + 2*NS)   // 38 rows of x_dbl
#define NCH 64           // scan chunks per sequence
#define CLL (LL/NCH)     // 49 steps per chunk

__device__ __forceinline__ float silu_f(float x) { return x / (1.f + __expf(-x)); }
__device__ __forceinline__ float softplus_f(float x) {
    return (x > 20.f) ? x : log1pf(__expf(x));
}

// K1: tiled GEMM  xz[o][l] = sum_c x[l][c] * w[o][c]; o<DI -> xc_t[o][l], o>=DI -> silu -> z_t
// 64l x 32o tile per block (grid 49x12=588 for parallelism), 256 threads.
__global__ __launch_bounds__(256) void k_inproj(
        const float* __restrict__ x, const float* __restrict__ w,
        float* __restrict__ xc_t, float* __restrict__ z_t) {
    __shared__ float xt[64 * 100];                 // 25.6 KB
    __shared__ float wt[32 * 100];                 // 12.8 KB
    const int l0 = blockIdx.x * 64;
    const int o0 = blockIdx.y * 32;
    const int tid = threadIdx.x;
    for (int i = tid; i < 64 * 96; i += 256) {
        int r = i / 96, c = i % 96;
        xt[r * 100 + c] = x[(size_t)(l0 + r) * DM + c];
    }
    for (int i = tid; i < 32 * 96; i += 256) {
        int r = i / 96, c = i % 96;
        wt[r * 100 + c] = w[(size_t)(o0 + r) * DM + c];
    }
    __syncthreads();
    const int tx = tid & 15, ty = tid >> 4;        // tx: o, ty: l
    float acc[4][2] = {};
    for (int c = 0; c < 96; c += 4) {
        float4 av[4], bv[2];
#pragma unroll
        for (int i = 0; i < 4; ++i) av[i] = *(const float4*)&xt[(ty + 16 * i) * 100 + c];
#pragma unroll
        for (int j = 0; j < 2; ++j) bv[j] = *(const float4*)&wt[(tx + 16 * j) * 100 + c];
#pragma unroll
        for (int i = 0; i < 4; ++i)
#pragma unroll
            for (int j = 0; j < 2; ++j) {
                acc[i][j] = fmaf(av[i].x, bv[j].x, acc[i][j]);
                acc[i][j] = fmaf(av[i].y, bv[j].y, acc[i][j]);
                acc[i][j] = fmaf(av[i].z, bv[j].z, acc[i][j]);
                acc[i][j] = fmaf(av[i].w, bv[j].w, acc[i][j]);
            }
    }
    __syncthreads();
    float* ot = xt;                                // reuse (32x65 <= 64x100)
#pragma unroll
    for (int j = 0; j < 2; ++j)
#pragma unroll
        for (int i = 0; i < 4; ++i)
            ot[(tx + 16 * j) * 65 + (ty + 16 * i)] = acc[i][j];
    __syncthreads();
    for (int i = tid; i < 32 * 64; i += 256) {
        int ol = i >> 6, ll = i & 63;
        float v = ot[ol * 65 + ll];
        int o = o0 + ol;
        if (o < DI) xc_t[(size_t)o * LL + l0 + ll] = v;
        else        z_t[(size_t)(o - DI) * LL + l0 + ll] = silu_f(v);
    }
}

// K2: depthwise 3x3 conv SAME + bias + silu, fused with spatial transpose.
__global__ __launch_bounds__(256) void k_convT(
        const float* __restrict__ xc_t, const float* __restrict__ cw,
        const float* __restrict__ cb, float* __restrict__ xconv, float* __restrict__ xs1) {
    __shared__ float in_s[LL];
    __shared__ float out_s[HH * 57];
    const int d = blockIdx.x;
    const int tid = threadIdx.x;
    const float* in = xc_t + (size_t)d * LL;
    for (int i = tid; i < LL; i += 256) in_s[i] = in[i];
    __syncthreads();
    const float b0 = cb[d];
    const float* wt = cw + d * 9;
    float w9[9];
#pragma unroll
    for (int i = 0; i < 9; ++i) w9[i] = wt[i];
    for (int l = tid; l < LL; l += 256) {
        int h = l / WW, w = l % WW;
        float acc = b0;
#pragma unroll
        for (int i = 0; i < 3; ++i) {
            int hh = h + i - 1;
            if (hh < 0 || hh >= HH) continue;
#pragma unroll
            for (int j = 0; j < 3; ++j) {
                int w2 = w + j - 1;
                if (w2 < 0 || w2 >= WW) continue;
                acc = fmaf(in_s[hh * WW + w2], w9[i * 3 + j], acc);
            }
        }
        acc = silu_f(acc);
        xconv[(size_t)d * LL + l] = acc;
        out_s[h * 57 + w] = acc;
    }
    __syncthreads();
    float* xo = xs1 + (size_t)d * LL;
    for (int s = tid; s < LL; s += 256)
        xo[s] = out_s[(s % HH) * 57 + s / HH];
}

// K3: x_dbl + delta fused, l-tile 32. Both operands LDS-staged.
// xt[d][sx] 24KB + wk_s[col][d] 24.6KB + dtS. Grid (98, 4).
__global__ __launch_bounds__(256) void k_xdblD(
        const float* __restrict__ xconv, const float* __restrict__ xs1,
        const float* __restrict__ pw, const float* __restrict__ dtw,
        const float* __restrict__ dtb,
        float* __restrict__ Bn, float* __restrict__ Cn, float* __restrict__ delta) {
    __shared__ float xt[DI * 32];                  // [d][sx], 24 KB
    __shared__ float wk_s[32 * DI];                // [col][d], 24.6 KB
    __shared__ float dtS[RR * 33];
    const int k = blockIdx.y;
    const int l0 = blockIdx.x * 32;
    const int tid = threadIdx.x;
    const float* in = (k & 1) ? xs1 : xconv;
    const float* wk = pw + (size_t)k * RN * DI;
    for (int i = tid; i < DI * 32; i += 256) {
        int d = i >> 5, lx = i & 31;
        xt[i] = in[(size_t)d * LL + l0 + lx];
    }
    // B/C weight rows contiguous: 32*192 floats starting at wk + RR*DI (16B-aligned)
    {
        const float4* src = (const float4*)(wk + RR * DI);
        float4* dst = (float4*)wk_s;
        for (int i = tid; i < (32 * DI) / 4; i += 256) dst[i] = src[i];
    }
    __syncthreads();
    // dt rows from xt (192 threads active)
    if (tid < RR * 32) {
        int r = tid >> 5, lx = tid & 31;
        const float* wr = wk + r * DI;
        float acc = 0.f;
#pragma unroll 8
        for (int d = 0; d < DI; ++d) acc = fmaf(xt[(d << 5) + lx], wr[d], acc);
        dtS[r * 33 + lx] = acc;
    }
    // B/C mini-GEMM: thread = (sx, cg); owns 4 cols {cg+8j}
    {
        const int sx = tid & 31, cg = tid >> 5;
        float acc4[4] = {};
        for (int d = 0; d < DI; d += 4) {
            float x0 = xt[(d + 0) * 32 + sx];
            float x1 = xt[(d + 1) * 32 + sx];
            float x2 = xt[(d + 2) * 32 + sx];
            float x3 = xt[(d + 3) * 32 + sx];
#pragma unroll
            for (int j = 0; j < 4; ++j) {
                float4 wv = *(const float4*)&wk_s[(cg + 8 * j) * DI + d];
                acc4[j] = fmaf(x0, wv.x, acc4[j]);
                acc4[j] = fmaf(x1, wv.y, acc4[j]);
                acc4[j] = fmaf(x2, wv.z, acc4[j]);
                acc4[j] = fmaf(x3, wv.w, acc4[j]);
            }
        }
        int s = l0 + sx;
#pragma unroll
        for (int j = 0; j < 4; ++j) {
            int col = cg + 8 * j;
            if (col < NS) Bn[((size_t)k * LL + s) * NS + col] = acc4[j];
            else          Cn[((size_t)k * LL + s) * NS + (col - NS)] = acc4[j];
        }
    }
    __syncthreads();
    // delta for all d of this k, this l-tile
    for (int oi = tid; oi < DI * 32; oi += 256) {
        int d = oi >> 5, sl = oi & 31;
        int kd = k * DI + d;
        const float* wr = dtw + (size_t)kd * RR;
        float acc = dtb[kd];
#pragma unroll
        for (int r = 0; r < RR; ++r) acc = fmaf(dtS[r * 33 + sl], wr[r], acc);
        delta[(size_t)kd * LL + l0 + sl] = softplus_f(acc);
    }
}

// K4: chunked selective scan, 64 chunks x 49 steps, one (k,d) per 1024-thread block.
__global__ __launch_bounds__(1024) void k_scan(
        const float* __restrict__ delta, const float* __restrict__ Bn,
        const float* __restrict__ Cn,
        const float* __restrict__ xconv, const float* __restrict__ xs1,
        const float* __restrict__ A_logs, const float* __restrict__ Ds,
        float* __restrict__ ybuf) {
    int b = blockIdx.x;
    int k = b / DI, d = b % DI;
    int tid = threadIdx.x;
    int c = tid >> 4, n = tid & 15;
    int kd = k * DI + d;
    float An = -__expf(A_logs[kd * NS + n]);
    float Dv = Ds[kd];
    const float* del = delta + (size_t)kd * LL;
    const float* uP  = ((k & 1) ? xs1 : xconv) + (size_t)d * LL;
    const float* Bb  = Bn + (size_t)k * LL * NS;
    const float* Cb  = Cn + (size_t)k * LL * NS;
    const bool fwd = (k < 2);
    const int t0 = c * CLL;
    const int im0 = fwd ? t0 : (LL - 1 - t0);
    const int stp = fwd ? 1 : -1;
    const int stpN = stp * NS;

    // Phase 1: chunk-local scan (h=0 start), track product of dA
    {
        const float* pd = del + im0;
        const float* pu = uP + im0;
        const float* pB = Bb + (size_t)im0 * NS + n;
        float P = 1.f, h = 0.f;
#pragma unroll 7
        for (int tl = 0; tl < CLL; ++tl) {
            float dl = *pd; float u = *pu; float Bv = *pB;
            pd += stp; pu += stp; pB += stpN;
            float dA = __expf(dl * An);
            h = fmaf(dA, h, dl * Bv * u);
            P *= dA;
        }
        __shared__ float sP[NCH * NS];
        __shared__ float sH[NCH * NS];
        sP[c * NS + n] = P;
        sH[c * NS + n] = h;
        __syncthreads();
        float hin = 0.f;
        for (int cc = 0; cc < c; ++cc)
            hin = fmaf(sP[cc * NS + n], hin, sH[cc * NS + n]);
        // Phase 2: rescan with carry, emit y (register-batched coalesced stores)
        float h2 = hin;
        float yreg[4];
        const float* pd2 = del + im0;
        const float* pu2 = uP + im0;
        const float* pB2 = Bb + (size_t)im0 * NS + n;
        const float* pC2 = Cb + (size_t)im0 * NS + n;
#pragma unroll 7
        for (int tl = 0; tl < CLL; ++tl) {
            float dl = *pd2; float u = *pu2; float Bv = *pB2; float Cv = *pC2;
            pd2 += stp; pu2 += stp; pB2 += stpN; pC2 += stpN;
            float dA = __expf(dl * An);
            h2 = fmaf(dA, h2, dl * Bv * u);
            float acc = h2 * Cv;
            acc += __shfl_xor(acc, 8, 64);
            acc += __shfl_xor(acc, 4, 64);
            acc += __shfl_xor(acc, 2, 64);
            acc += __shfl_xor(acc, 1, 64);
            acc = fmaf(Dv, u, acc);
            if ((tl & 15) == n) yreg[tl >> 4] = acc;
        }
        float* yo = ybuf + (size_t)kd * LL;
#pragma unroll
        for (int j = 0; j < 3; ++j) {
            int t = t0 + j * 16 + n;
            int im = fwd ? t : (LL - 1 - t);
            yo[im] = yreg[j];
        }
        if (n == 0) {
            int t = t0 + 48;
            int im = fwd ? t : (LL - 1 - t);
            yo[im] = yreg[3];
        }
    }
}

// K5: merge 4 directions + LayerNorm + gate(z) + out-proj (DI->DM), 16 l per block.
__global__ __launch_bounds__(256) void k_lnout(
        const float* __restrict__ ybuf, const float* __restrict__ z_t,
        const float* __restrict__ lnw, const float* __restrict__ lnb,
        const float* __restrict__ ow, float* __restrict__ out) {
    __shared__ float ow_s[48 * 196];               // 37.6 KB
    __shared__ float yv_s[16 * 196];               // 12.5 KB
    __shared__ float mean_s[16], inv_s[16];
    const int l0 = blockIdx.x * 16;
    const int tid = threadIdx.x;
    for (int i = tid; i < DI * 16; i += 256) {
        int d = i >> 4, ll = i & 15;
        int l = l0 + ll;
        int pT = (l % WW) * HH + l / WW;
        float v = ybuf[((size_t)(0 * DI) + d) * LL + l]
                + ybuf[((size_t)(2 * DI) + d) * LL + l]
                + ybuf[((size_t)(1 * DI) + d) * LL + pT]
                + ybuf[((size_t)(3 * DI) + d) * LL + pT];
        yv_s[ll * 196 + d] = v;
    }
    __syncthreads();
    {
        int ll = tid >> 4, e = tid & 15;
        float s1 = 0.f;
#pragma unroll
        for (int m = 0; m < 12; ++m) s1 += yv_s[ll * 196 + e + 16 * m];
        s1 += __shfl_xor(s1, 8, 64);
        s1 += __shfl_xor(s1, 4, 64);
        s1 += __shfl_xor(s1, 2, 64);
        s1 += __shfl_xor(s1, 1, 64);
        float mean = s1 * (1.f / DI);
        float s2 = 0.f;
#pragma unroll
        for (int m = 0; m < 12; ++m) {
            float dv = yv_s[ll * 196 + e + 16 * m] - mean;
            s2 = fmaf(dv, dv, s2);
        }
        s2 += __shfl_xor(s2, 8, 64);
        s2 += __shfl_xor(s2, 4, 64);
        s2 += __shfl_xor(s2, 2, 64);
        s2 += __shfl_xor(s2, 1, 64);
        if (e == 0) {
            mean_s[ll] = mean;
            inv_s[ll] = rsqrtf(s2 * (1.f / DI) + 1e-5f);
        }
    }
    __syncthreads();
    for (int i = tid; i < DI * 16; i += 256) {
        int d = i >> 4, ll = i & 15;
        float yn = (yv_s[ll * 196 + d] - mean_s[ll]) * inv_s[ll] * lnw[d] + lnb[d];
        yv_s[ll * 196 + d] = yn * z_t[(size_t)d * LL + l0 + ll];
    }
    __syncthreads();
    const int lg = tid >> 4, og = tid & 15;
#pragma unroll
    for (int pass = 0; pass < 2; ++pass) {
        for (int i = tid; i < 48 * DI; i += 256) {
            int o = i / DI, dd = i % DI;
            ow_s[o * 196 + dd] = ow[(size_t)(pass * 48 + o) * DI + dd];
        }
        __syncthreads();
        float acc[3] = {0.f, 0.f, 0.f};
        for (int dd = 0; dd < DI; dd += 4) {
            float4 yv4 = *(const float4*)&yv_s[lg * 196 + dd];
#pragma unroll
            for (int j = 0; j < 3; ++j) {
                float4 ov = *(const float4*)&ow_s[(og + 16 * j) * 196 + dd];
                acc[j] = fmaf(yv4.x, ov.x, acc[j]);
                acc[j] = fmaf(yv4.y, ov.y, acc[j]);
                acc[j] = fmaf(yv4.z, ov.z, acc[j]);
                acc[j] = fmaf(yv4.w, ov.w, acc[j]);
            }
        }
#pragma unroll
        for (int j = 0; j < 3; ++j)
            out[(size_t)(l0 + lg) * DM + pass * 48 + og + 16 * j] = acc[j];
        __syncthreads();
    }
}

extern "C" void kernel_launch(void* const* d_in, const int* in_sizes, int n_in,
                              void* d_out, int out_size, void* d_ws, size_t ws_size,
                              hipStream_t stream) {
    const float* x    = (const float*)d_in[0];
    const float* ipw  = (const float*)d_in[1];
    const float* cw   = (const float*)d_in[2];
    const float* cb   = (const float*)d_in[3];
    const float* xpw  = (const float*)d_in[4];
    const float* dtw  = (const float*)d_in[5];
    const float* dtb  = (const float*)d_in[6];
    const float* alog = (const float*)d_in[7];
    const float* Dsp  = (const float*)d_in[8];
    const float* lnw  = (const float*)d_in[9];
    const float* lnb  = (const float*)d_in[10];
    const float* ow   = (const float*)d_in[11];
    float* out = (float*)d_out;

    float* ws    = (float*)d_ws;
    float* xc_t  = ws;                            // DI*LL
    float* z_t   = xc_t + DI * LL;                // DI*LL
    float* xconv = z_t + DI * LL;                 // DI*LL
    float* xs1   = xconv + DI * LL;               // DI*LL
    float* Bn    = xs1 + DI * LL;                 // KK*LL*NS
    float* Cn    = Bn + (size_t)KK * LL * NS;     // KK*LL*NS
    float* delta = Cn + (size_t)KK * LL * NS;     // KK*DI*LL
    float* ybuf  = delta + (size_t)KK * DI * LL;  // KK*DI*LL

    k_inproj <<<dim3(LL / 64, 12), 256, 0, stream>>>(x, ipw, xc_t, z_t);
    k_convT  <<<DI, 256, 0, stream>>>(xc_t, cw, cb, xconv, xs1);
    k_xdblD  <<<dim3(LL / 32, KK), 256, 0, stream>>>(xconv, xs1, xpw, dtw, dtb, Bn, Cn, delta);
    k_scan   <<<KK * DI, 1024, 0, stream>>>(delta, Bn, Cn, xconv, xs1, alog, Dsp, ybuf);
    k_lnout  <<<LL / 16, 256, 0, stream>>>(ybuf, z_t, lnw, lnb, ow, out);
}